// Round 2
// baseline (220.975 us; speedup 1.0000x reference)
//
#include <hip/hip_runtime.h>

// BinaryAggregationLayer: batch=4096, in_width=8192, out_width=8191.
// dest[i] = min(i, 8190)  =>  out[b][j] = x[b][j] for j<8190,
//                             out[b][8190] = 0.5*(x[b][8190]+x[b][8191])
// then clip to +-10000. Pure memory-bound strided copy.
//
// Flat mapping: o = b*8191 + j  ->  input i = o + b.
// Output quads (o0 = 4t) are 16B-aligned; input is misaligned by a = b&3
// floats (wave-uniform within a row). Fast path: 2 aligned float4 loads
// covering the 8-float window + select-by-phase + 1 float4 store
// (3 VMEM/16B vs 5 for scalar loads). Slow path (1 quad per row, where
// j0 >= 8187: merge element and/or row crossing): scalar, verified R1.

#define OUTW   8191u
#define CLAMPV 10000.0f

__global__ __launch_bounds__(256) void bagg_copy_kernel(
    const float* __restrict__ x, float* __restrict__ out, unsigned int total4) {
    unsigned int t = blockIdx.x * blockDim.x + threadIdx.x;
    if (t >= total4) return;

    unsigned int o0 = t * 4u;                 // flat output index of this quad
    unsigned int b  = o0 / OUTW;              // magic-mul division
    unsigned int j0 = o0 - b * OUTW;

    float4 o4;
    if (j0 < 8187u) {
        // No merge element, no row crossing in this quad.
        unsigned int i0   = o0 + b;           // input flat index of element 0
        unsigned int a    = b & 3u;           // misalignment phase (== i0 & 3)
        unsigned int base = (i0 - a) >> 2;    // aligned float4 index
        const float4* __restrict__ in4 = reinterpret_cast<const float4*>(x);
        float4 A = in4[base];
        float4 B = in4[base + 1u];            // in-bounds for all fast-path quads
        if (a == 0u)      o4 = A;
        else if (a == 1u) o4 = make_float4(A.y, A.z, A.w, B.x);
        else if (a == 2u) o4 = make_float4(A.z, A.w, B.x, B.y);
        else              o4 = make_float4(A.w, B.x, B.y, B.z);
    } else {
        // Slow path: covers j = 8187..8190 (merge node) and the wrap into
        // the next row's leading elements.
        float r[4];
        unsigned int j = j0, bb = b;
#pragma unroll
        for (int k = 0; k < 4; ++k) {
            unsigned int i = o0 + (unsigned int)k + bb;
            float v = x[i];
            if (j == OUTW - 1u) v = 0.5f * (v + x[i + 1u]);
            r[k] = v;
            ++j;
            if (j == OUTW) { j = 0u; ++bb; }
        }
        o4 = make_float4(r[0], r[1], r[2], r[3]);
    }

    o4.x = fminf(fmaxf(o4.x, -CLAMPV), CLAMPV);
    o4.y = fminf(fmaxf(o4.y, -CLAMPV), CLAMPV);
    o4.z = fminf(fmaxf(o4.z, -CLAMPV), CLAMPV);
    o4.w = fminf(fmaxf(o4.w, -CLAMPV), CLAMPV);

    reinterpret_cast<float4*>(out)[t] = o4;
}

extern "C" void kernel_launch(void* const* d_in, const int* in_sizes, int n_in,
                              void* d_out, int out_size, void* d_ws, size_t ws_size,
                              hipStream_t stream) {
    const float* x = (const float*)d_in[0];
    float* out = (float*)d_out;

    const unsigned int total  = 4096u * OUTW;     // 33,550,336
    const unsigned int total4 = total / 4u;       // 8,387,584 (exact)
    const unsigned int block  = 256;
    const unsigned int grid   = (total4 + block - 1) / block;

    bagg_copy_kernel<<<grid, block, 0, stream>>>(x, out, total4);
}